// Round 2
// baseline (9093.642 us; speedup 1.0000x reference)
//
#include <hip/hip_runtime.h>
#include <math.h>

// Sinkhorn OT layer, B=8192, C=256, L=100, LAMBD=1.
//
// U = log_u - ||x_i||^2, V = log_v - ||y_j||^2, G[i][j] = 2*dot(x_i,y_j):
//   U[i] = -LSE_j(G[i][j] + V[j]),  V[j] = -LSE_i(G[i][j] + U[i])
// init V[j] = -||y_j||^2. Final: out[i] = y[argmax_j(G[i][j]+V[j])].
//
// R6: G as 24-bit fixed point (q=2^-15, err 1.5e-5): Glo u16 (128 MiB) +
// Ghi s8 (64 MiB). 9367 -> 7498 us.
// R7: FUSE row+col passes. Each block owns a 32-row strip; per 4-row
// sub-chunk: sweep A computes U for those rows (block LSE reduce, U stays
// in LDS -- never global), sweep B re-reads the same 96 KiB (L2-resident:
// 32 blocks/XCD x 96 KiB ~ 3 MiB < 4 MiB L2) accumulating per-column
// (m,s) ENTIRELY IN REGISTERS (thread t owns cols {e*1024+t}, e=0..7).
// Per-iter HBM: 384 MiB -> ~224 MiB (G once + 32 MiB partials r/w).
// Also: single-exp online LSE (E=exp(-|d|) + selects) halves trans-pipe
// work; V stored transposed V'[e*1024+c]=V[c*8+e] so all V accesses are
// coalesced and the fused kernel keeps V in 8 registers per thread.
//
// Kept: int24 G, conflict-free GEMM, device-global V (plain loads/stores,
// kernel-boundary visibility), smallest-index argmax tie-break.

#define B 8192
#define C 256
#define LITERS 100
#define RPB 32                     // rows per fused block (=> 256 chunks)
#define SUB 4                      // rows per L2-reuse window
#define NCH (B / RPB)              // 256 partial chunks

#define QS 65536.0f                // (2*acc) * 32768 == acc * 65536
#define QI 3.0517578125e-5f        // 2^-15

typedef float f32x4 __attribute__((ext_vector_type(4)));
typedef unsigned short u16x8 __attribute__((ext_vector_type(8)));
typedef signed char i8x8 __attribute__((ext_vector_type(8)));

// V in transposed layout: g_Vp[e*1024 + c] = V[c*8 + e]
__device__ __align__(16) float g_Vp[B];

// ---------------- init: V[j] = -||y_j||^2 (transposed store) ----------------
__global__ __launch_bounds__(256) void init_V(const float* __restrict__ y) {
    int wave = threadIdx.x >> 6;
    int lane = threadIdx.x & 63;
    int row = blockIdx.x * 4 + wave;
    const f32x4* yr = (const f32x4*)(y + (size_t)row * C);
    f32x4 v = yr[lane];
    float s = v.x * v.x + v.y * v.y + v.z * v.z + v.w * v.w;
    #pragma unroll
    for (int off = 32; off; off >>= 1) s += __shfl_down(s, off, 64);
    if (lane == 0) g_Vp[(row & 7) * 1024 + (row >> 3)] = -s;
}

// ---------------- GEMM: G = 2 * x @ y^T, quantized to int24 ----------------
#define GT 64
#define GKT 64
#define LSTR (GKT + 4)   // 68 floats; float4-aligned offsets

__global__ __launch_bounds__(256) void gemm_G(const float* __restrict__ x,
                                              const float* __restrict__ y,
                                              unsigned short* __restrict__ Glo,
                                              signed char* __restrict__ Ghi) {
    __shared__ float As[GT][LSTR];   // [i][k]
    __shared__ float Bs[GT][LSTR];   // [j][k]
    int bi = blockIdx.y * GT;
    int bj = blockIdx.x * GT;
    int t = threadIdx.x;
    int tx = t & 15, ty = t >> 4;
    float acc[4][4] = {};
    for (int kk = 0; kk < C; kk += GKT) {
        #pragma unroll
        for (int l = 0; l < 4; ++l) {
            int idx = t + l * 256;         // float4 index in tile
            int r = idx >> 4;              // tile row 0..63
            int c4 = idx & 15;             // float4 col 0..15
            *(f32x4*)&As[r][c4 * 4] =
                *(const f32x4*)(x + (size_t)(bi + r) * C + kk + c4 * 4);
            *(f32x4*)&Bs[r][c4 * 4] =
                *(const f32x4*)(y + (size_t)(bj + r) * C + kk + c4 * 4);
        }
        __syncthreads();
        #pragma unroll
        for (int k4 = 0; k4 < GKT / 4; ++k4) {
            f32x4 a[4], b[4];
            #pragma unroll
            for (int ii = 0; ii < 4; ++ii)
                a[ii] = *(const f32x4*)&As[ty * 4 + ii][k4 * 4];
            #pragma unroll
            for (int jj = 0; jj < 4; ++jj)
                b[jj] = *(const f32x4*)&Bs[tx + 16 * jj][k4 * 4];
            #pragma unroll
            for (int ii = 0; ii < 4; ++ii)
                #pragma unroll
                for (int jj = 0; jj < 4; ++jj) {
                    acc[ii][jj] = fmaf(a[ii].x, b[jj].x, acc[ii][jj]);
                    acc[ii][jj] = fmaf(a[ii].y, b[jj].y, acc[ii][jj]);
                    acc[ii][jj] = fmaf(a[ii].z, b[jj].z, acc[ii][jj]);
                    acc[ii][jj] = fmaf(a[ii].w, b[jj].w, acc[ii][jj]);
                }
        }
        __syncthreads();
    }
    #pragma unroll
    for (int ii = 0; ii < 4; ++ii) {
        int gi = bi + ty * 4 + ii;
        #pragma unroll
        for (int jj = 0; jj < 4; ++jj) {
            size_t idx = (size_t)gi * B + bj + tx + 16 * jj;
            float gs = acc[ii][jj] * QS;                       // G * 2^15
            gs = fminf(fmaxf(gs, -8388607.0f), 8388607.0f);    // int24 clamp
            int v = __float2int_rn(gs);
            Glo[idx] = (unsigned short)(v & 0xFFFF);
            Ghi[idx] = (signed char)(v >> 16);
        }
    }
}

// ---------------- fused row+col pass ----------------
// Block = 1024 threads, owns rows [chunk*32, chunk*32+32).
// Thread t owns columns j = t*8..t*8+7 (group c=t), i.e. pos = e*1024+t.
__global__ __launch_bounds__(1024) void fused_iter(
        const unsigned short* __restrict__ Glo,
        const signed char* __restrict__ Ghi,
        float* __restrict__ pm, float* __restrict__ ps) {
    int t = threadIdx.x;
    int chunk = blockIdx.x;
    int i0 = chunk * RPB;
    int wave = t >> 6, lane = t & 63;

    // this thread's 8 V values (constant across the whole iteration)
    float vreg[8];
    #pragma unroll
    for (int e = 0; e < 8; ++e) vreg[e] = g_Vp[e * 1024 + t];

    // per-column online-LSE state, in registers
    float cm[8], cs[8];
    #pragma unroll
    for (int e = 0; e < 8; ++e) { cm[e] = -INFINITY; cs[e] = 0.0f; }

    __shared__ float wred[16][SUB][2];   // per-wave (m,s) per row
    __shared__ float Usub[SUB];

    for (int sc = 0; sc < RPB / SUB; ++sc) {
        int r0 = i0 + sc * SUB;
        // ---- load sub-chunk (hoisted for ILP) ----
        u16x8 lo[SUB]; i8x8 hi[SUB];
        #pragma unroll
        for (int r = 0; r < SUB; ++r) {
            lo[r] = ((const u16x8*)(Glo + (size_t)(r0 + r) * B))[t];
            hi[r] = ((const i8x8*)(Ghi + (size_t)(r0 + r) * B))[t];
        }
        // ---- sweep A: per-row LSE (thread-local over 8 cols) ----
        float rm[SUB], rs[SUB];
        #pragma unroll
        for (int r = 0; r < SUB; ++r) {
            float m = -INFINITY, s = 0.0f;
            #pragma unroll
            for (int e = 0; e < 8; ++e) {
                int q = ((int)hi[r][e] << 16) | (int)lo[r][e];
                float val = fmaf((float)q, QI, vreg[e]);
                float d = val - m;
                float E = __expf(-fabsf(d));     // exp(-inf)=0 on first elem
                bool nm = d > 0.0f;
                s = nm ? fmaf(s, E, 1.0f) : (s + E);
                m = nm ? val : m;
            }
            rm[r] = m; rs[r] = s;
        }
        // wave butterfly reduce per row
        #pragma unroll
        for (int r = 0; r < SUB; ++r) {
            float m = rm[r], s = rs[r];
            #pragma unroll
            for (int off = 1; off < 64; off <<= 1) {
                float mo = __shfl_xor(m, off, 64);
                float so = __shfl_xor(s, off, 64);
                float m2 = fmaxf(m, mo);
                s = s * __expf(m - m2) + so * __expf(mo - m2);
                m = m2;
            }
            if (lane == 0) { wred[wave][r][0] = m; wred[wave][r][1] = s; }
        }
        __syncthreads();
        if (t < SUB) {
            float m = -INFINITY, s = 0.0f;
            #pragma unroll
            for (int w = 0; w < 16; ++w) {
                float mc = wred[w][t][0], sc = wred[w][t][1];
                float d = mc - m;
                float E = __expf(-fabsf(d));
                bool nm = d > 0.0f;
                s = nm ? fmaf(s, E, sc) : fmaf(sc, E, s);
                m = nm ? mc : m;
            }
            Usub[t] = -(m + logf(s));
        }
        __syncthreads();
        // ---- sweep B: re-read (L2 hit) + per-column accumulate ----
        #pragma unroll
        for (int r = 0; r < SUB; ++r) {
            lo[r] = ((const u16x8*)(Glo + (size_t)(r0 + r) * B))[t];
            hi[r] = ((const i8x8*)(Ghi + (size_t)(r0 + r) * B))[t];
        }
        #pragma unroll
        for (int r = 0; r < SUB; ++r) {
            float u = Usub[r];
            #pragma unroll
            for (int e = 0; e < 8; ++e) {
                int q = ((int)hi[r][e] << 16) | (int)lo[r][e];
                float val = fmaf((float)q, QI, u);
                float d = val - cm[e];
                float E = __expf(-fabsf(d));
                bool nm = d > 0.0f;
                cs[e] = nm ? fmaf(cs[e], E, 1.0f) : (cs[e] + E);
                cm[e] = nm ? val : cm[e];
            }
        }
        __syncthreads();   // protect wred/Usub for next sub-chunk
    }
    #pragma unroll
    for (int e = 0; e < 8; ++e) {
        pm[(size_t)chunk * B + e * 1024 + t] = cm[e];
        ps[(size_t)chunk * B + e * 1024 + t] = cs[e];
    }
}

// ---------------- combine: V'[pos] = -(LSE of 256 chunk partials) ----------------
// 256 blocks x 256 threads; block handles 32 pos; thread (pl,g) reduces 32 chunks.
__global__ __launch_bounds__(256) void col_combine(const float* __restrict__ pm,
                                                   const float* __restrict__ ps) {
    int t = threadIdx.x;
    int pl = t & 31;
    int g = t >> 5;               // 0..7
    int pos = blockIdx.x * 32 + pl;
    float m = -INFINITY, s = 0.0f;
    #pragma unroll 8
    for (int c = g * 32; c < g * 32 + 32; ++c) {
        float mc = pm[(size_t)c * B + pos];
        float sc = ps[(size_t)c * B + pos];
        float d = mc - m;
        float E = __expf(-fabsf(d));
        bool nm = d > 0.0f;
        s = nm ? fmaf(s, E, sc) : fmaf(sc, E, s);
        m = nm ? mc : m;
    }
    __shared__ float lm[8][32], ls[8][32];
    lm[g][pl] = m; ls[g][pl] = s;
    __syncthreads();
    if (t < 32) {
        float m0 = lm[0][t], s0 = ls[0][t];
        #pragma unroll
        for (int gg = 1; gg < 8; ++gg) {
            float mc = lm[gg][t], sc = ls[gg][t];
            float d = mc - m0;
            float E = __expf(-fabsf(d));
            bool nm = d > 0.0f;
            s0 = nm ? fmaf(s0, E, sc) : fmaf(sc, E, s0);
            m0 = nm ? mc : m0;
        }
        g_Vp[pos] = -(m0 + logf(s0));
    }
}

// ---------------- argmax + gather: out[i] = y[argmax_j(G[i][j]+V[j])] ----------------
__global__ __launch_bounds__(256) void argmax_out(const unsigned short* __restrict__ Glo,
                                                  const signed char* __restrict__ Ghi,
                                                  const float* __restrict__ y,
                                                  float* __restrict__ out) {
    int i = blockIdx.x;
    int t = threadIdx.x;
    const u16x8* lo8 = (const u16x8*)(Glo + (size_t)i * B);
    const i8x8*  hi8 = (const i8x8*)(Ghi + (size_t)i * B);
    float best = -INFINITY;
    int bj = B;
    #pragma unroll
    for (int it = 0; it < 4; ++it) {
        int idx = it * 256 + t;
        u16x8 lo = lo8[idx];
        i8x8  hi = hi8[idx];
        #pragma unroll
        for (int k = 0; k < 8; ++k) {
            float vk = g_Vp[k * 1024 + idx];      // V[idx*8+k], transposed layout
            int q = ((int)hi[k] << 16) | (int)lo[k];
            float val = fmaf((float)q, QI, vk);
            int j = idx * 8 + k;
            if (val > best) { best = val; bj = j; }
        }
    }
    __shared__ float bm[256];
    __shared__ int   bidx[256];
    bm[t] = best; bidx[t] = bj;
    __syncthreads();
    #pragma unroll
    for (int off = 128; off; off >>= 1) {
        if (t < off) {
            float om = bm[t + off]; int oj = bidx[t + off];
            if (om > bm[t] || (om == bm[t] && oj < bidx[t])) { bm[t] = om; bidx[t] = oj; }
        }
        __syncthreads();
    }
    int jstar = bidx[0];
    out[(size_t)i * C + t] = y[(size_t)jstar * C + t];
}

extern "C" void kernel_launch(void* const* d_in, const int* in_sizes, int n_in,
                              void* d_out, int out_size, void* d_ws, size_t ws_size,
                              hipStream_t stream) {
    const float* x = (const float*)d_in[0];
    const float* y = (const float*)d_in[1];
    float* out = (float*)d_out;
    unsigned short* Glo = (unsigned short*)d_ws;                           // 128 MiB
    signed char*    Ghi = (signed char*)((char*)d_ws + (size_t)B * B * 2); // +64 MiB
    float* pm = (float*)((char*)d_ws + (size_t)B * B * 3);                 // +8 MiB
    float* ps = (float*)((char*)d_ws + (size_t)B * B * 3 + (size_t)NCH * B * 4); // +8 MiB

    init_V<<<B / 4, 256, 0, stream>>>(y);
    gemm_G<<<dim3(B / GT, B / GT), 256, 0, stream>>>(x, y, Glo, Ghi);
    for (int l = 0; l < LITERS; ++l) {
        fused_iter<<<NCH, 1024, 0, stream>>>(Glo, Ghi, pm, ps);
        col_combine<<<B / 32, 256, 0, stream>>>(pm, ps);
    }
    argmax_out<<<B, 256, 0, stream>>>(Glo, Ghi, y, out);
}

// Round 4
// 8056.586 us; speedup vs baseline: 1.1287x; 1.1287x over previous
//
#include <hip/hip_runtime.h>
#include <math.h>

// Sinkhorn OT layer, B=8192, C=256, L=100, LAMBD=1.
//
// U = log_u - ||x_i||^2, V = log_v - ||y_j||^2, G[i][j] = 2*dot(x_i,y_j):
//   U[i] = -LSE_j(G[i][j] + V[j]),  V[j] = -LSE_i(G[i][j] + U[i])
// init V[j] = -||y_j||^2. Final: out[i] = y[argmax_j(G[i][j]+V[j])].
//
// R6: int24 G (Glo u16 128 MiB + Ghi s8 64 MiB). 9367 -> 7498 us.
// R7 (9094, FAILED): fused row+col; block-wide exp-butterflies + 16
// barriers -> occupancy 9%, VALUBusy 15%.
// R8 (CRASH): linear column sums: (a) dropped the V_old term of the
// update (V_new = V_old - log(colsum), NOT -log(colsum)); (b) f32 exp
// underflow -> colsum=0 -> V=inf -> NaN -> argmax fell through to
// bj=B -> OOB read of y.
// R9: fusion kept, both bugs fixed, restructured for latency:
//  - row phase: each WAVE owns 2 complete rows -> online (m,s) purely
//    in-wave (shfl only, no LDS, no barriers). W_i = m_i + log s_i.
//  - col phase: thread owns 8 cols; cs[e] += exp(G+V_j - W_i) = P_ij
//    (row-stochastic, in [0,1], no overflow); 32 independent row loads
//    -> deep MLP. 2 barriers per dispatch total (vs 16).
//  - combine: V[j] -= log(max(colsum, 1e-30)); clamp handles all-
//    underflow columns (self-correcting: update is a contraction and
//    argmax is invariant to the common u/v shift).
// Per-iter G traffic: 192 MiB once from HBM/L3 + L2/L3-hot re-read.
//
// Kept: int24 G (q=2^-15, err 1.5e-5 ~ accepted fp32 noise class),
// conflict-free f32 GEMM, natural V layout (transposed layout dropped --
// no longer needed), smallest-index argmax tie-break.

#define B 8192
#define C 256
#define LITERS 100
#define RPB 32                     // rows per fused block (=> 256 chunks)
#define NCH (B / RPB)              // 256 partial chunks

#define QS 65536.0f                // (2*acc) * 32768 == acc * 65536
#define QI 3.0517578125e-5f        // 2^-15

typedef float f32x4 __attribute__((ext_vector_type(4)));
typedef unsigned short u16x8 __attribute__((ext_vector_type(8)));
typedef signed char i8x8 __attribute__((ext_vector_type(8)));

__device__ __align__(16) float g_V[B];

// ---------------- init: V[j] = -||y_j||^2 ----------------
__global__ __launch_bounds__(256) void init_V(const float* __restrict__ y) {
    int wave = threadIdx.x >> 6;
    int lane = threadIdx.x & 63;
    int row = blockIdx.x * 4 + wave;
    const f32x4* yr = (const f32x4*)(y + (size_t)row * C);
    f32x4 v = yr[lane];
    float s = v.x * v.x + v.y * v.y + v.z * v.z + v.w * v.w;
    #pragma unroll
    for (int off = 32; off; off >>= 1) s += __shfl_down(s, off, 64);
    if (lane == 0) g_V[row] = -s;
}

// ---------------- GEMM: G = 2 * x @ y^T, quantized to int24 ----------------
#define GT 64
#define GKT 64
#define LSTR (GKT + 4)   // 68 floats; float4-aligned offsets

__global__ __launch_bounds__(256) void gemm_G(const float* __restrict__ x,
                                              const float* __restrict__ y,
                                              unsigned short* __restrict__ Glo,
                                              signed char* __restrict__ Ghi) {
    __shared__ float As[GT][LSTR];   // [i][k]
    __shared__ float Bs[GT][LSTR];   // [j][k]
    int bi = blockIdx.y * GT;
    int bj = blockIdx.x * GT;
    int t = threadIdx.x;
    int tx = t & 15, ty = t >> 4;
    float acc[4][4] = {};
    for (int kk = 0; kk < C; kk += GKT) {
        #pragma unroll
        for (int l = 0; l < 4; ++l) {
            int idx = t + l * 256;         // float4 index in tile
            int r = idx >> 4;              // tile row 0..63
            int c4 = idx & 15;             // float4 col 0..15
            *(f32x4*)&As[r][c4 * 4] =
                *(const f32x4*)(x + (size_t)(bi + r) * C + kk + c4 * 4);
            *(f32x4*)&Bs[r][c4 * 4] =
                *(const f32x4*)(y + (size_t)(bj + r) * C + kk + c4 * 4);
        }
        __syncthreads();
        #pragma unroll
        for (int k4 = 0; k4 < GKT / 4; ++k4) {
            f32x4 a[4], b[4];
            #pragma unroll
            for (int ii = 0; ii < 4; ++ii)
                a[ii] = *(const f32x4*)&As[ty * 4 + ii][k4 * 4];
            #pragma unroll
            for (int jj = 0; jj < 4; ++jj)
                b[jj] = *(const f32x4*)&Bs[tx + 16 * jj][k4 * 4];
            #pragma unroll
            for (int ii = 0; ii < 4; ++ii)
                #pragma unroll
                for (int jj = 0; jj < 4; ++jj) {
                    acc[ii][jj] = fmaf(a[ii].x, b[jj].x, acc[ii][jj]);
                    acc[ii][jj] = fmaf(a[ii].y, b[jj].y, acc[ii][jj]);
                    acc[ii][jj] = fmaf(a[ii].z, b[jj].z, acc[ii][jj]);
                    acc[ii][jj] = fmaf(a[ii].w, b[jj].w, acc[ii][jj]);
                }
        }
        __syncthreads();
    }
    #pragma unroll
    for (int ii = 0; ii < 4; ++ii) {
        int gi = bi + ty * 4 + ii;
        #pragma unroll
        for (int jj = 0; jj < 4; ++jj) {
            size_t idx = (size_t)gi * B + bj + tx + 16 * jj;
            float gs = acc[ii][jj] * QS;                       // G * 2^15
            gs = fminf(fmaxf(gs, -8388607.0f), 8388607.0f);    // int24 clamp
            int v = __float2int_rn(gs);
            Glo[idx] = (unsigned short)(v & 0xFFFF);
            Ghi[idx] = (signed char)(v >> 16);
        }
    }
}

// ---------------- fused row+col pass ----------------
// Block = 1024 threads (16 waves), owns rows [chunk*32, chunk*32+32).
// Row phase: wave w owns rows i0+2w, i0+2w+1 entirely (in-wave online LSE,
// no barriers). Col phase: thread t owns cols 8t..8t+7, accumulates
// cs[e] += exp(val - W_i) = P_ij over the 32 rows.
__global__ __launch_bounds__(1024) void fused_iter(
        const unsigned short* __restrict__ Glo,
        const signed char* __restrict__ Ghi,
        float* __restrict__ pm) {
    __shared__ float V_lds[B];        // 32 KiB
    __shared__ float W_lds[RPB];
    int t = threadIdx.x;
    int chunk = blockIdx.x;
    int i0 = chunk * RPB;
    int wave = t >> 6, lane = t & 63;

    // ---- stage V into LDS (once) ----
    {
        f32x4 a = *(const f32x4*)(g_V + 8 * t);
        f32x4 b = *(const f32x4*)(g_V + 8 * t + 4);
        *(f32x4*)&V_lds[8 * t] = a;
        *(f32x4*)&V_lds[8 * t + 4] = b;
    }
    __syncthreads();

    // ---- row phase: rows r0, r1 fully within this wave ----
    int r0 = i0 + 2 * wave;
    int r1 = r0 + 1;
    const u16x8* lo0p = (const u16x8*)(Glo + (size_t)r0 * B);
    const i8x8*  hi0p = (const i8x8*)(Ghi + (size_t)r0 * B);
    const u16x8* lo1p = (const u16x8*)(Glo + (size_t)r1 * B);
    const i8x8*  hi1p = (const i8x8*)(Ghi + (size_t)r1 * B);
    float m0 = -INFINITY, s0 = 0.0f, m1 = -INFINITY, s1 = 0.0f;
    #pragma unroll 2
    for (int c = 0; c < 16; ++c) {
        int vi = c * 64 + lane;          // u16x8 index within row
        u16x8 lo0 = lo0p[vi];
        i8x8  hi0 = hi0p[vi];
        u16x8 lo1 = lo1p[vi];
        i8x8  hi1 = hi1p[vi];
        f32x4 va = *(const f32x4*)&V_lds[vi * 8];
        f32x4 vb = *(const f32x4*)&V_lds[vi * 8 + 4];
        float vv[8] = {va.x, va.y, va.z, va.w, vb.x, vb.y, vb.z, vb.w};
        #pragma unroll
        for (int e = 0; e < 8; ++e) {
            int q0 = ((int)hi0[e] << 16) | (int)lo0[e];
            float v0 = fmaf((float)q0, QI, vv[e]);
            float d0 = v0 - m0;
            float E0 = __expf(-fabsf(d0));       // exp(-inf)=0 first elem
            bool n0 = d0 > 0.0f;
            s0 = n0 ? fmaf(s0, E0, 1.0f) : (s0 + E0);
            m0 = n0 ? v0 : m0;
            int q1 = ((int)hi1[e] << 16) | (int)lo1[e];
            float v1 = fmaf((float)q1, QI, vv[e]);
            float d1 = v1 - m1;
            float E1 = __expf(-fabsf(d1));
            bool n1 = d1 > 0.0f;
            s1 = n1 ? fmaf(s1, E1, 1.0f) : (s1 + E1);
            m1 = n1 ? v1 : m1;
        }
    }
    // in-wave butterfly combine of (m,s) per row
    #pragma unroll
    for (int off = 1; off < 64; off <<= 1) {
        float mo = __shfl_xor(m0, off, 64), so = __shfl_xor(s0, off, 64);
        float m2 = fmaxf(m0, mo);
        s0 = s0 * __expf(m0 - m2) + so * __expf(mo - m2);
        m0 = m2;
        float mp = __shfl_xor(m1, off, 64), sp = __shfl_xor(s1, off, 64);
        float m3 = fmaxf(m1, mp);
        s1 = s1 * __expf(m1 - m3) + sp * __expf(mp - m3);
        m1 = m3;
    }
    if (lane == 0) {
        W_lds[2 * wave]     = m0 + logf(s0);   // = -U[r0]
        W_lds[2 * wave + 1] = m1 + logf(s1);
    }
    __syncthreads();

    // ---- col phase: thread t owns cols 8t..8t+7 ----
    float vr[8];
    {
        f32x4 a = *(const f32x4*)&V_lds[8 * t];
        f32x4 b = *(const f32x4*)&V_lds[8 * t + 4];
        vr[0] = a.x; vr[1] = a.y; vr[2] = a.z; vr[3] = a.w;
        vr[4] = b.x; vr[5] = b.y; vr[6] = b.z; vr[7] = b.w;
    }
    float cs[8] = {0.f, 0.f, 0.f, 0.f, 0.f, 0.f, 0.f, 0.f};
    #pragma unroll 4
    for (int r = 0; r < RPB; ++r) {
        float W = W_lds[r];
        u16x8 lo = ((const u16x8*)(Glo + (size_t)(i0 + r) * B))[t];
        i8x8  hi = ((const i8x8*)(Ghi + (size_t)(i0 + r) * B))[t];
        #pragma unroll
        for (int e = 0; e < 8; ++e) {
            int q = ((int)hi[e] << 16) | (int)lo[e];
            float ex = __expf(fmaf((float)q, QI, vr[e]) - W);  // P_ij in [0,1]
            cs[e] += ex;
        }
    }
    f32x4 o0 = {cs[0], cs[1], cs[2], cs[3]};
    f32x4 o1 = {cs[4], cs[5], cs[6], cs[7]};
    *(f32x4*)&pm[(size_t)chunk * B + 8 * t] = o0;
    *(f32x4*)&pm[(size_t)chunk * B + 8 * t + 4] = o1;
}

// ---------------- combine: V[j] -= log(sum of 256 chunk partials) ----------------
// 256 blocks x 256 threads; block handles 32 cols; thread (pl,g) sums 32 chunks.
__global__ __launch_bounds__(256) void col_combine(const float* __restrict__ pm) {
    int t = threadIdx.x;
    int pl = t & 31;
    int g = t >> 5;               // 0..7
    int j = blockIdx.x * 32 + pl;
    float s = 0.0f;
    #pragma unroll 8
    for (int c = g * 32; c < g * 32 + 32; ++c)
        s += pm[(size_t)c * B + j];
    __shared__ float ls[8][32];
    ls[g][pl] = s;
    __syncthreads();
    if (t < 32) {
        float s0 = ls[0][t];
        #pragma unroll
        for (int gg = 1; gg < 8; ++gg) s0 += ls[gg][t];
        int jj = blockIdx.x * 32 + t;
        // clamp: all-underflow columns get a bounded +69 push (self-correcting)
        g_V[jj] -= logf(fmaxf(s0, 1e-30f));
    }
}

// ---------------- argmax + gather: out[i] = y[argmax_j(G[i][j]+V[j])] ----------------
__global__ __launch_bounds__(256) void argmax_out(const unsigned short* __restrict__ Glo,
                                                  const signed char* __restrict__ Ghi,
                                                  const float* __restrict__ y,
                                                  float* __restrict__ out) {
    int i = blockIdx.x;
    int t = threadIdx.x;
    const u16x8* lo8 = (const u16x8*)(Glo + (size_t)i * B);
    const i8x8*  hi8 = (const i8x8*)(Ghi + (size_t)i * B);
    const f32x4* v4 = (const f32x4*)g_V;
    float best = -INFINITY;
    int bj = 0;                              // safe init (never OOB)
    #pragma unroll
    for (int it = 0; it < 4; ++it) {
        int idx = it * 256 + t;
        u16x8 lo = lo8[idx];
        i8x8  hi = hi8[idx];
        f32x4 va = v4[idx * 2], vb = v4[idx * 2 + 1];
        float vv[8] = {va.x, va.y, va.z, va.w, vb.x, vb.y, vb.z, vb.w};
        #pragma unroll
        for (int k = 0; k < 8; ++k) {
            int q = ((int)hi[k] << 16) | (int)lo[k];
            float val = fmaf((float)q, QI, vv[k]);
            int j = idx * 8 + k;
            if (val > best) { best = val; bj = j; }
        }
    }
    __shared__ float bm[256];
    __shared__ int   bidx[256];
    bm[t] = best; bidx[t] = bj;
    __syncthreads();
    #pragma unroll
    for (int off = 128; off; off >>= 1) {
        if (t < off) {
            float om = bm[t + off]; int oj = bidx[t + off];
            if (om > bm[t] || (om == bm[t] && oj < bidx[t])) { bm[t] = om; bidx[t] = oj; }
        }
        __syncthreads();
    }
    int jstar = bidx[0];
    out[(size_t)i * C + t] = y[(size_t)jstar * C + t];
}

extern "C" void kernel_launch(void* const* d_in, const int* in_sizes, int n_in,
                              void* d_out, int out_size, void* d_ws, size_t ws_size,
                              hipStream_t stream) {
    const float* x = (const float*)d_in[0];
    const float* y = (const float*)d_in[1];
    float* out = (float*)d_out;
    unsigned short* Glo = (unsigned short*)d_ws;                           // 128 MiB
    signed char*    Ghi = (signed char*)((char*)d_ws + (size_t)B * B * 2); // +64 MiB
    float* pm = (float*)((char*)d_ws + (size_t)B * B * 3);                 // +8 MiB

    init_V<<<B / 4, 256, 0, stream>>>(y);
    gemm_G<<<dim3(B / GT, B / GT), 256, 0, stream>>>(x, y, Glo, Ghi);
    for (int l = 0; l < LITERS; ++l) {
        fused_iter<<<NCH, 1024, 0, stream>>>(Glo, Ghi, pm);
        col_combine<<<B / 32, 256, 0, stream>>>(pm);
    }
    argmax_out<<<B, 256, 0, stream>>>(Glo, Ghi, y, out);
}